// Round 9
// baseline (220.762 us; speedup 1.0000x reference)
//
#include <hip/hip_runtime.h>
#include <cstdint>
#include <cstddef>

// ---------------------------------------------------------------------------
// FlashSparseAttention on MI355X (gfx950)
// R8 baseline (211.24 us measured): swizzled GEMMs, attn reg-prefetch +
//   XOR-swizzled LDS + split-KV x2.
// R12: (1) cvt_all widened to 8 floats/thread; (2) combine fused into Wo GEMM
//   (gemm_wo). attn + QKV GEMM byte-identical to R8.
// R13-R16: identical resubmits (broker infra failures; R12 unmeasured).
// R17: + s_setprio(1) around attn MFMA clusters (QK^T, PV). Zero correctness
//   risk (pure scheduler hint); co-resident independent blocks give the wave
//   role-diversity where setprio pays (m191 attn case). QKV GEMM remains the
//   byte-identical cross-round control.
// ---------------------------------------------------------------------------

typedef __bf16 bf16_t;
typedef bf16_t bf16x4_t __attribute__((ext_vector_type(4)));
typedef bf16_t bf16x8_t __attribute__((ext_vector_type(8)));
typedef float f32x4_t __attribute__((ext_vector_type(4)));

__device__ __forceinline__ void async_copy16(void* lds_base, const void* gsrc) {
  auto g = reinterpret_cast<__attribute__((address_space(1))) void*>(
      reinterpret_cast<uintptr_t>(gsrc));
  auto l = reinterpret_cast<__attribute__((address_space(3))) void*>(
      static_cast<uint32_t>(reinterpret_cast<uintptr_t>(lds_base)));
  __builtin_amdgcn_global_load_lds(g, l, 16, 0, 0);
}

// ---------------------------------------------------------------------------
// fp32 -> bf16: merged conversion of hidden/Wq/Wk/Wv/Wo (one launch)
// 8 floats/thread: 2x float4 load + one 16B bf16x8 store.
// ---------------------------------------------------------------------------
__global__ __launch_bounds__(256) void cvt_all(const float* __restrict__ hs,
                                               const float* __restrict__ wq,
                                               const float* __restrict__ wk,
                                               const float* __restrict__ wv,
                                               const float* __restrict__ wo,
                                               bf16_t* __restrict__ regA,
                                               bf16_t* __restrict__ regB,
                                               bf16_t* __restrict__ regWo) {
  const int b = blockIdx.x;
  const float* src;
  bf16_t* dst;
  int rel;
  if (b < 2048) { src = hs; dst = regA; rel = b; }
  else if (b < 4096) { src = wq; dst = regB; rel = b - 2048; }
  else if (b < 4608) { src = wk; dst = regB + 4194304; rel = b - 4096; }
  else if (b < 5120) { src = wv; dst = regB + 5242880; rel = b - 4608; }
  else { src = wo; dst = regWo; rel = b - 5120; }
  const int i = (rel * 256 + threadIdx.x) * 8;
  float4 v0 = *(const float4*)(src + i);
  float4 v1 = *(const float4*)(src + i + 4);
  bf16x8_t o = {(bf16_t)v0.x, (bf16_t)v0.y, (bf16_t)v0.z, (bf16_t)v0.w,
                (bf16_t)v1.x, (bf16_t)v1.y, (bf16_t)v1.z, (bf16_t)v1.w};
  *(bf16x8_t*)(dst + i) = o;
}

// ---------------------------------------------------------------------------
// NT GEMM: C[M,N] = A[M,K] * B[N,K]^T, 64x128 tile, BK=64, 4 waves.
// LDS XOR swizzle (chunk q of row r at slot q^(r&7)); store side permutes
// the GLOBAL source address, keeping global_load_lds + coalescing.
// ROPE fused in epilogue for output cols < 2560.  (QKV projection only.)
// (byte-identical to R8 — cross-round control)
// ---------------------------------------------------------------------------
template <typename OutT, bool ROPE>
__global__ __launch_bounds__(256) void gemm_bt64(const bf16_t* __restrict__ A,
                                                 const bf16_t* __restrict__ B,
                                                 OutT* __restrict__ C,
                                                 int M, int N, int K) {
  __shared__ bf16_t As[64 * 64];
  __shared__ bf16_t Bs[128 * 64];
  const int tid = threadIdx.x;
  const int lane = tid & 63;
  const int quad = lane >> 4;
  const int l15 = lane & 15;
  const int l7 = l15 & 7;
  const int wave = tid >> 6;
  const int bm = blockIdx.x * 64;
  const int bn = blockIdx.y * 128;
  const int wm = (wave >> 1) * 32;
  const int wn32 = (wave & 1) * 32;
  const int coff[4] = {wn32, wn32 + 16, wn32 + 64, wn32 + 80};

  f32x4_t acc[2][4] = {};

  for (int k0 = 0; k0 < K; k0 += 64) {
#pragma unroll
    for (int it = 0; it < 2; ++it) {
      const int slot = it * 256 + tid;          // 16B chunk index
      const int r = slot >> 3;
      const int q = (slot & 7) ^ (r & 7);       // swizzled source chunk
      const int wbase = it * 2048 + (tid & 192) * 8;
      async_copy16(As + wbase, A + (size_t)(bm + r) * K + k0 + q * 8);
    }
#pragma unroll
    for (int it = 0; it < 4; ++it) {
      const int slot = it * 256 + tid;
      const int r = slot >> 3;
      const int q = (slot & 7) ^ (r & 7);
      const int wbase = it * 2048 + (tid & 192) * 8;
      async_copy16(Bs + wbase, B + (size_t)(bn + r) * K + k0 + q * 8);
    }
    __syncthreads();
#pragma unroll
    for (int kk = 0; kk < 64; kk += 32) {
      const int kc = kk >> 3;
      bf16x8_t af[2], bfv[4];
#pragma unroll
      for (int i = 0; i < 2; ++i)
        af[i] = *(const bf16x8_t*)(As + (wm + i * 16 + l15) * 64 +
                                   (((kc + quad) ^ l7) * 8));
#pragma unroll
      for (int i = 0; i < 4; ++i)
        bfv[i] = *(const bf16x8_t*)(Bs + (coff[i] + l15) * 64 +
                                    (((kc + quad) ^ l7) * 8));
#pragma unroll
      for (int mi = 0; mi < 2; ++mi)
#pragma unroll
        for (int ni = 0; ni < 4; ++ni)
          acc[mi][ni] = __builtin_amdgcn_mfma_f32_16x16x32_bf16(
              af[mi], bfv[ni], acc[mi][ni], 0, 0, 0);
    }
    __syncthreads();
  }

  if (ROPE && bn < 2560) {  // q/k columns; v (>=2560) skips
#pragma unroll
    for (int pair = 0; pair < 2; ++pair) {
      const int i_d = wn32 + pair * 16 + l15;  // head-relative d in [0,64)
      const float inv = exp2f(-(float)i_d * 0.20762050593045702f);
#pragma unroll
      for (int mi = 0; mi < 2; ++mi) {
#pragma unroll
        for (int r = 0; r < 4; ++r) {
          const int s_row = bm + wm + mi * 16 + quad * 4 + r;
          float sn, cs;
          sincosf((float)s_row * inv, &sn, &cs);
          const float x0 = acc[mi][pair][r];
          const float x1 = acc[mi][pair + 2][r];
          acc[mi][pair][r] = x0 * cs - x1 * sn;
          acc[mi][pair + 2][r] = x1 * cs + x0 * sn;
        }
      }
    }
  }

  // C/D layout: col = lane&15, row = quad*4 + reg
#pragma unroll
  for (int mi = 0; mi < 2; ++mi) {
#pragma unroll
    for (int r = 0; r < 4; ++r) {
      const int row = bm + wm + mi * 16 + quad * 4 + r;
#pragma unroll
      for (int ni = 0; ni < 4; ++ni)
        C[(size_t)row * N + bn + coff[ni] + l15] = (OutT)acc[mi][ni][r];
    }
  }
}

// ---------------------------------------------------------------------------
// Wo GEMM with fused split-KV combine:
//   A[M=2048,K=2048] = (O0 + O1) * rcp(l0 + l1) converted to bf16 on the fly
//   (reg-staged, XOR-swizzled ds_write_b128); B = Wo bf16 via global_load_lds.
// Each K-step (64 cols) lies within one head (h = k0>>7), so the l lookup is
// uniform per K-step. Numerics identical to the old combine->bf16->GEMM path.
// ---------------------------------------------------------------------------
__global__ __launch_bounds__(256) void gemm_wo(const float* __restrict__ Op,
                                               const float* __restrict__ lp,
                                               const bf16_t* __restrict__ B,
                                               float* __restrict__ C) {
  __shared__ bf16_t As[64 * 64];
  __shared__ bf16_t Bs[128 * 64];
  const int tid = threadIdx.x;
  const int lane = tid & 63;
  const int quad = lane >> 4;
  const int l15 = lane & 15;
  const int l7 = l15 & 7;
  const int wave = tid >> 6;
  const int bm = blockIdx.x * 64;
  const int bn = blockIdx.y * 128;
  const int wm = (wave >> 1) * 32;
  const int wn32 = (wave & 1) * 32;
  const int coff[4] = {wn32, wn32 + 16, wn32 + 64, wn32 + 80};
  const int K = 2048, N = 2048;

  // A staging coords: thread owns rows {r0, r0+32}, LDS position p within row;
  // position p of row r holds global chunk q = p ^ (r&7) (same swizzle as
  // gemm_bt64, applied on the load side instead of the source address).
  const int p = tid & 7;
  const int r0 = tid >> 3;

  f32x4_t acc[2][4] = {};

  for (int k0 = 0; k0 < K; k0 += 64) {
    const int h = k0 >> 7;  // head index, uniform for this K-step

    // issue A global loads first (latency starts earliest)
    float4 a0[2], a1[2], b0[2], b1[2];
    float lv[2];
#pragma unroll
    for (int it = 0; it < 2; ++it) {
      const int r = it * 32 + r0;
      const int q = p ^ (r & 7);
      const float* s0 = Op + (size_t)(bm + r) * 2048 + k0 + q * 8;
      const float* s1 = s0 + 4194304;
      a0[it] = *(const float4*)(s0);
      a1[it] = *(const float4*)(s0 + 4);
      b0[it] = *(const float4*)(s1);
      b1[it] = *(const float4*)(s1 + 4);
      lv[it] = lp[(bm + r) * 16 + h] + lp[(2048 + bm + r) * 16 + h];
    }

    // B tile: async global->LDS (independent of A path)
#pragma unroll
    for (int it = 0; it < 4; ++it) {
      const int slot = it * 256 + tid;
      const int r = slot >> 3;
      const int q = (slot & 7) ^ (r & 7);
      const int wbase = it * 2048 + (tid & 192) * 8;
      async_copy16(Bs + wbase, B + (size_t)(bn + r) * K + k0 + q * 8);
    }

    // combine + convert + swizzled LDS write
#pragma unroll
    for (int it = 0; it < 2; ++it) {
      const int r = it * 32 + r0;
      const float inv = __builtin_amdgcn_rcpf(lv[it]);
      bf16x8_t o = {(bf16_t)((a0[it].x + b0[it].x) * inv),
                    (bf16_t)((a0[it].y + b0[it].y) * inv),
                    (bf16_t)((a0[it].z + b0[it].z) * inv),
                    (bf16_t)((a0[it].w + b0[it].w) * inv),
                    (bf16_t)((a1[it].x + b1[it].x) * inv),
                    (bf16_t)((a1[it].y + b1[it].y) * inv),
                    (bf16_t)((a1[it].z + b1[it].z) * inv),
                    (bf16_t)((a1[it].w + b1[it].w) * inv)};
      *(bf16x8_t*)(As + r * 64 + p * 8) = o;
    }
    __syncthreads();
#pragma unroll
    for (int kk = 0; kk < 64; kk += 32) {
      const int kc = kk >> 3;
      bf16x8_t af[2], bfv[4];
#pragma unroll
      for (int i = 0; i < 2; ++i)
        af[i] = *(const bf16x8_t*)(As + (wm + i * 16 + l15) * 64 +
                                   (((kc + quad) ^ l7) * 8));
#pragma unroll
      for (int i = 0; i < 4; ++i)
        bfv[i] = *(const bf16x8_t*)(Bs + (coff[i] + l15) * 64 +
                                    (((kc + quad) ^ l7) * 8));
#pragma unroll
      for (int mi = 0; mi < 2; ++mi)
#pragma unroll
        for (int ni = 0; ni < 4; ++ni)
          acc[mi][ni] = __builtin_amdgcn_mfma_f32_16x16x32_bf16(
              af[mi], bfv[ni], acc[mi][ni], 0, 0, 0);
    }
    __syncthreads();
  }

#pragma unroll
  for (int mi = 0; mi < 2; ++mi) {
#pragma unroll
    for (int r = 0; r < 4; ++r) {
      const int row = bm + wm + mi * 16 + quad * 4 + r;
#pragma unroll
      for (int ni = 0; ni < 4; ++ni)
        C[(size_t)row * N + bn + coff[ni] + l15] = acc[mi][ni][r];
    }
  }
}

// ---------------------------------------------------------------------------
// Flash attention, causal, GQA, split-KV x2 (additive fp32 partials via
// fixed-max softmax).  1024 blocks; complementary mapping: the 4 blocks
// co-resident on a CU (j, j+256 over both halves) total exactly 33 kv-tiles.
// R6 body: register K/V prefetch during compute, 2 barriers/tile.
// XOR-swizzled LDS, no padding: exactly 40 KB -> 4 blocks/CU at ~120 VGPR.
// R17: s_setprio(1) around the two MFMA clusters (co-resident independent
// blocks -> wave role-diversity; zero numeric effect).
// ---------------------------------------------------------------------------
__global__ __launch_bounds__(256) void attn_kernel(
    const bf16_t* __restrict__ qkv, float* __restrict__ Op,
    float* __restrict__ lp) {
  __shared__ bf16_t Ks[64 * 128];    // [key][d], chunk ^ (key&15)
  __shared__ bf16_t Vt[128 * 64];    // [d][key], chunk ^ (d&7)
  __shared__ bf16_t Ps[4 * 16 * 64]; // per-wave, chunk ^ (row&7)
  const int tid = threadIdx.x;
  const int lane = tid & 63;
  const int wave = tid >> 6;
  const int quad = lane >> 4;
  const int l15 = lane & 15;
  const int l7 = l15 & 7;
  const int j = blockIdx.x;
  const int half = j >> 9;
  const int j2 = j & 511;
  const int qb = (j2 < 256) ? (31 - (j2 >> 4)) : ((j2 - 256) >> 4);
  const int h = j2 & 15;
  const int kvh = h >> 2;
  const int nh0 = (qb + 2) >> 1;             // tiles in half 0
  const int kbS = half ? nh0 : 0;
  const int kbE = half ? (qb + 1) : nh0;
  const float scale = 0.08838834764831845f;  // 1/sqrt(128)

  // staging coordinates (iteration-invariant)
  const int rk0 = tid >> 4;        // K row within 16-row group
  const int cq = tid & 15;         // K col chunk
  const int dv2 = lane * 2;        // V d-pair base

  // Q fragments (A-operand)
  bf16x8_t qf[4];
  {
    const bf16_t* qbase =
        qkv + (size_t)(qb * 64 + wave * 16 + l15) * 3072 + h * 128 + quad * 8;
#pragma unroll
    for (int kf = 0; kf < 4; ++kf) qf[kf] = *(const bf16x8_t*)(qbase + kf * 32);
  }

  f32x4_t o[8] = {};
  float lsum[4] = {0.f, 0.f, 0.f, 0.f};

  bf16x8_t kreg[4];
  uint32_t vbuf[2][8];
  auto load_tile = [&](int kb) {
    const bf16_t* kbase = qkv + (size_t)(kb * 64) * 3072 + 2048 + kvh * 128;
    const bf16_t* vbase = qkv + (size_t)(kb * 64) * 3072 + 2560 + kvh * 128;
#pragma unroll
    for (int it = 0; it < 4; ++it)
      kreg[it] =
          *(const bf16x8_t*)(kbase + (size_t)(it * 16 + rk0) * 3072 + cq * 8);
#pragma unroll
    for (int it = 0; it < 2; ++it) {
      const int kg8 = it * 4 + wave;  // key octet 0..7
#pragma unroll
      for (int t = 0; t < 8; ++t)
        vbuf[it][t] =
            *(const uint32_t*)(vbase + (size_t)(kg8 * 8 + t) * 3072 + dv2);
    }
  };

  if (kbS < kbE) {
    load_tile(kbS);

    for (int kb = kbS; kb < kbE; ++kb) {
      __syncthreads();  // prev iteration's Ks/Vt reads complete
#pragma unroll
      for (int it = 0; it < 4; ++it)
        *(bf16x8_t*)(Ks + (it * 16 + rk0) * 128 + ((cq ^ rk0) * 8)) = kreg[it];
#pragma unroll
      for (int it = 0; it < 2; ++it) {
        const int kg8 = it * 4 + wave;
        bf16x8_t lov, hiv;
#pragma unroll
        for (int t = 0; t < 8; ++t) {
          const uint32_t u = vbuf[it][t];
          lov[t] = __builtin_bit_cast(bf16_t, (unsigned short)(u & 0xffff));
          hiv[t] = __builtin_bit_cast(bf16_t, (unsigned short)(u >> 16));
        }
        *(bf16x8_t*)(Vt + (size_t)dv2 * 64 + ((kg8 ^ (dv2 & 7)) * 8)) = lov;
        *(bf16x8_t*)(Vt + (size_t)(dv2 + 1) * 64 +
                     ((kg8 ^ ((dv2 + 1) & 7)) * 8)) = hiv;
      }
      __syncthreads();
      if (kb + 1 < kbE) load_tile(kb + 1);  // overlaps compute below

      // S = Q * K^T
      f32x4_t sc[4] = {};
      __builtin_amdgcn_s_setprio(1);
#pragma unroll
      for (int kf = 0; kf < 4; ++kf) {
#pragma unroll
        for (int ni = 0; ni < 4; ++ni) {
          bf16x8_t bfr = *(const bf16x8_t*)(Ks + (ni * 16 + l15) * 128 +
                                            (((kf * 4 + quad) ^ l15) * 8));
          sc[ni] = __builtin_amdgcn_mfma_f32_16x16x32_bf16(qf[kf], bfr, sc[ni],
                                                           0, 0, 0);
        }
      }
      __builtin_amdgcn_s_setprio(0);

      // fixed-max softmax: p = exp(s*scale - 16); causal mask -> -100 arg
      float p[4][4];
#pragma unroll
      for (int r = 0; r < 4; ++r) {
        const int sq = qb * 64 + wave * 16 + quad * 4 + r;
#pragma unroll
        for (int ni = 0; ni < 4; ++ni) {
          float arg = fmaf(sc[ni][r], scale, -16.0f);
          if (kb == qb && (kb * 64 + ni * 16 + l15) > sq) arg = -100.0f;
          const float e = __expf(arg);
          p[ni][r] = e;
          lsum[r] += e;
        }
      }

      // P: C layout -> LDS (wave-private, swizzled)
      bf16_t* pw = Ps + wave * 16 * 64;
#pragma unroll
      for (int ni = 0; ni < 4; ++ni)
#pragma unroll
        for (int r = 0; r < 4; ++r) {
          const int prow = quad * 4 + r;
          pw[prow * 64 + (((ni * 2 + (l15 >> 3)) ^ (prow & 7)) * 8) + l7] =
              (bf16_t)p[ni][r];
        }

      // O += P * V
      __builtin_amdgcn_s_setprio(1);
#pragma unroll
      for (int kf = 0; kf < 2; ++kf) {
        bf16x8_t af =
            *(const bf16x8_t*)(pw + l15 * 64 + (((kf * 4 + quad) ^ l7) * 8));
#pragma unroll
        for (int ni = 0; ni < 8; ++ni) {
          bf16x8_t bfr = *(const bf16x8_t*)(Vt + (ni * 16 + l15) * 64 +
                                            (((kf * 4 + quad) ^ l7) * 8));
          o[ni] =
              __builtin_amdgcn_mfma_f32_16x16x32_bf16(af, bfr, o[ni], 0, 0, 0);
        }
      }
      __builtin_amdgcn_s_setprio(0);
    }
  }

  // epilogue: reduce l across 16 lanes; store fp32 partials
#pragma unroll
  for (int m = 1; m <= 8; m <<= 1)
#pragma unroll
    for (int r = 0; r < 4; ++r) lsum[r] += __shfl_xor(lsum[r], m, 64);

  float* obase = Op + (size_t)half * 4194304 +
                 (size_t)(qb * 64 + wave * 16 + quad * 4) * 2048 + h * 128 + l15;
#pragma unroll
  for (int r = 0; r < 4; ++r) {
#pragma unroll
    for (int ni = 0; ni < 8; ++ni)
      obase[(size_t)r * 2048 + ni * 16] = o[ni][r];
    if (l15 == 0) {
      const int row = qb * 64 + wave * 16 + quad * 4 + r;
      lp[(half * 2048 + row) * 16 + h] = lsum[r];
    }
  }
}

// ---------------------------------------------------------------------------
// ws layout (~61.3 MB, liveness-reused):
//   regA  [0,    8 MB)   hs_bf16 (dead after QKV gemm)
//   regB  [8,   20.6 MB) Wqkv_bf16        (dead after QKV gemm)
//   Opart [8,   40 MB)   fp32 O partials  (overwrites regB)
//   regC  [40,  52.6 MB) qkv bf16 (RoPE applied in GEMM epilogue)
//   regWo [53,  61 MB)   Wo_bf16
//   lpart [61,  61.25)   fp32 l partials [2][2048][16]
// ---------------------------------------------------------------------------
extern "C" void kernel_launch(void* const* d_in, const int* in_sizes, int n_in,
                              void* d_out, int out_size, void* d_ws, size_t ws_size,
                              hipStream_t stream) {
  const float* hidden = (const float*)d_in[0];
  const float* Wq = (const float*)d_in[1];
  const float* Wk = (const float*)d_in[2];
  const float* Wv = (const float*)d_in[3];
  const float* Wo = (const float*)d_in[4];

  char* ws = (char*)d_ws;
  bf16_t* regA = (bf16_t*)ws;
  bf16_t* regB = (bf16_t*)(ws + (size_t)(8u << 20));
  float* Opart = (float*)(ws + (size_t)(8u << 20));
  bf16_t* regC = (bf16_t*)(ws + (size_t)(40u << 20));
  bf16_t* regWo = (bf16_t*)(ws + (size_t)(53u << 20));
  float* lpart = (float*)(ws + (size_t)(61u << 20));

  cvt_all<<<7168, 256, 0, stream>>>(hidden, Wq, Wk, Wv, Wo, regA, regB, regWo);

  // qkv = hidden @ [Wq;Wk;Wv]^T, RoPE fused -> regC [2048,3072]
  gemm_bt64<bf16_t, true><<<dim3(32, 24), 256, 0, stream>>>(regA, regB, regC,
                                                            2048, 3072, 2048);

  attn_kernel<<<1024, 256, 0, stream>>>(regC, Opart, lpart);

  // Wo GEMM with fused combine: reads fp32 partials directly
  gemm_wo<<<dim3(32, 16), 256, 0, stream>>>(Opart, lpart, regWo,
                                            (float*)d_out);
}

// Round 10
// 219.519 us; speedup vs baseline: 1.0057x; 1.0057x over previous
//
#include <hip/hip_runtime.h>
#include <cstdint>
#include <cstddef>

// ---------------------------------------------------------------------------
// FlashSparseAttention on MI355X (gfx950)
// R8 baseline: 211.24 us measured. R17 (cvt 8-wide + combine fused into Wo
//   GEMM + attn setprio): 220.76 us measured — REGRESSION.
// Post-mortem: fused combine turned the Wo GEMM's A operand from 8 MB bf16
//   (x16 re-reads = 128 MB, cache-resident) into 33.5 MB fp32 partials
//   (x16 = 536 MB L2/L3 traffic). L3 hits are not free; ~matches the +25 us
//   miss vs prediction. absmax 0.0059->0.0156 from rcpf confirms the fused
//   path was live.
// R18: revert fusion (separate combine_kernel, exact R8 arithmetic with
//   1.0f/l -> absmax should return to exactly 0.005922; Wo GEMM reads bf16
//   regA again). KEEP cvt_all 8-wide; widen combine to 8-wide (same proven
//   pattern). KEEP attn setprio (profiled attn faster; worst case ~-1.5%).
// ---------------------------------------------------------------------------

typedef __bf16 bf16_t;
typedef bf16_t bf16x4_t __attribute__((ext_vector_type(4)));
typedef bf16_t bf16x8_t __attribute__((ext_vector_type(8)));
typedef float f32x4_t __attribute__((ext_vector_type(4)));

__device__ __forceinline__ void async_copy16(void* lds_base, const void* gsrc) {
  auto g = reinterpret_cast<__attribute__((address_space(1))) void*>(
      reinterpret_cast<uintptr_t>(gsrc));
  auto l = reinterpret_cast<__attribute__((address_space(3))) void*>(
      static_cast<uint32_t>(reinterpret_cast<uintptr_t>(lds_base)));
  __builtin_amdgcn_global_load_lds(g, l, 16, 0, 0);
}

// ---------------------------------------------------------------------------
// fp32 -> bf16: merged conversion of hidden/Wq/Wk/Wv/Wo (one launch)
// 8 floats/thread: 2x float4 load + one 16B bf16x8 store.
// ---------------------------------------------------------------------------
__global__ __launch_bounds__(256) void cvt_all(const float* __restrict__ hs,
                                               const float* __restrict__ wq,
                                               const float* __restrict__ wk,
                                               const float* __restrict__ wv,
                                               const float* __restrict__ wo,
                                               bf16_t* __restrict__ regA,
                                               bf16_t* __restrict__ regB,
                                               bf16_t* __restrict__ regWo) {
  const int b = blockIdx.x;
  const float* src;
  bf16_t* dst;
  int rel;
  if (b < 2048) { src = hs; dst = regA; rel = b; }
  else if (b < 4096) { src = wq; dst = regB; rel = b - 2048; }
  else if (b < 4608) { src = wk; dst = regB + 4194304; rel = b - 4096; }
  else if (b < 5120) { src = wv; dst = regB + 5242880; rel = b - 4608; }
  else { src = wo; dst = regWo; rel = b - 5120; }
  const int i = (rel * 256 + threadIdx.x) * 8;
  float4 v0 = *(const float4*)(src + i);
  float4 v1 = *(const float4*)(src + i + 4);
  bf16x8_t o = {(bf16_t)v0.x, (bf16_t)v0.y, (bf16_t)v0.z, (bf16_t)v0.w,
                (bf16_t)v1.x, (bf16_t)v1.y, (bf16_t)v1.z, (bf16_t)v1.w};
  *(bf16x8_t*)(dst + i) = o;
}

// ---------------------------------------------------------------------------
// NT GEMM: C[M,N] = A[M,K] * B[N,K]^T, 64x128 tile, BK=64, 4 waves.
// LDS XOR swizzle (chunk q of row r at slot q^(r&7)); store side permutes
// the GLOBAL source address, keeping global_load_lds + coalescing.
// ROPE fused in epilogue for output cols < 2560.  (QKV projection only.)
// (byte-identical to R8 — cross-round control)
// ---------------------------------------------------------------------------
template <typename OutT, bool ROPE>
__global__ __launch_bounds__(256) void gemm_bt64(const bf16_t* __restrict__ A,
                                                 const bf16_t* __restrict__ B,
                                                 OutT* __restrict__ C,
                                                 int M, int N, int K) {
  __shared__ bf16_t As[64 * 64];
  __shared__ bf16_t Bs[128 * 64];
  const int tid = threadIdx.x;
  const int lane = tid & 63;
  const int quad = lane >> 4;
  const int l15 = lane & 15;
  const int l7 = l15 & 7;
  const int wave = tid >> 6;
  const int bm = blockIdx.x * 64;
  const int bn = blockIdx.y * 128;
  const int wm = (wave >> 1) * 32;
  const int wn32 = (wave & 1) * 32;
  const int coff[4] = {wn32, wn32 + 16, wn32 + 64, wn32 + 80};

  f32x4_t acc[2][4] = {};

  for (int k0 = 0; k0 < K; k0 += 64) {
#pragma unroll
    for (int it = 0; it < 2; ++it) {
      const int slot = it * 256 + tid;          // 16B chunk index
      const int r = slot >> 3;
      const int q = (slot & 7) ^ (r & 7);       // swizzled source chunk
      const int wbase = it * 2048 + (tid & 192) * 8;
      async_copy16(As + wbase, A + (size_t)(bm + r) * K + k0 + q * 8);
    }
#pragma unroll
    for (int it = 0; it < 4; ++it) {
      const int slot = it * 256 + tid;
      const int r = slot >> 3;
      const int q = (slot & 7) ^ (r & 7);
      const int wbase = it * 2048 + (tid & 192) * 8;
      async_copy16(Bs + wbase, B + (size_t)(bn + r) * K + k0 + q * 8);
    }
    __syncthreads();
#pragma unroll
    for (int kk = 0; kk < 64; kk += 32) {
      const int kc = kk >> 3;
      bf16x8_t af[2], bfv[4];
#pragma unroll
      for (int i = 0; i < 2; ++i)
        af[i] = *(const bf16x8_t*)(As + (wm + i * 16 + l15) * 64 +
                                   (((kc + quad) ^ l7) * 8));
#pragma unroll
      for (int i = 0; i < 4; ++i)
        bfv[i] = *(const bf16x8_t*)(Bs + (coff[i] + l15) * 64 +
                                    (((kc + quad) ^ l7) * 8));
#pragma unroll
      for (int mi = 0; mi < 2; ++mi)
#pragma unroll
        for (int ni = 0; ni < 4; ++ni)
          acc[mi][ni] = __builtin_amdgcn_mfma_f32_16x16x32_bf16(
              af[mi], bfv[ni], acc[mi][ni], 0, 0, 0);
    }
    __syncthreads();
  }

  if (ROPE && bn < 2560) {  // q/k columns; v (>=2560) skips
#pragma unroll
    for (int pair = 0; pair < 2; ++pair) {
      const int i_d = wn32 + pair * 16 + l15;  // head-relative d in [0,64)
      const float inv = exp2f(-(float)i_d * 0.20762050593045702f);
#pragma unroll
      for (int mi = 0; mi < 2; ++mi) {
#pragma unroll
        for (int r = 0; r < 4; ++r) {
          const int s_row = bm + wm + mi * 16 + quad * 4 + r;
          float sn, cs;
          sincosf((float)s_row * inv, &sn, &cs);
          const float x0 = acc[mi][pair][r];
          const float x1 = acc[mi][pair + 2][r];
          acc[mi][pair][r] = x0 * cs - x1 * sn;
          acc[mi][pair + 2][r] = x1 * cs + x0 * sn;
        }
      }
    }
  }

  // C/D layout: col = lane&15, row = quad*4 + reg
#pragma unroll
  for (int mi = 0; mi < 2; ++mi) {
#pragma unroll
    for (int r = 0; r < 4; ++r) {
      const int row = bm + wm + mi * 16 + quad * 4 + r;
#pragma unroll
      for (int ni = 0; ni < 4; ++ni)
        C[(size_t)row * N + bn + coff[ni] + l15] = (OutT)acc[mi][ni][r];
    }
  }
}

// ---------------------------------------------------------------------------
// Flash attention, causal, GQA, split-KV x2 (additive fp32 partials via
// fixed-max softmax).  1024 blocks; complementary mapping: the 4 blocks
// co-resident on a CU (j, j+256 over both halves) total exactly 33 kv-tiles.
// R6 body: register K/V prefetch during compute, 2 barriers/tile.
// XOR-swizzled LDS, no padding: exactly 40 KB.
// R17: s_setprio(1) around the two MFMA clusters (kept in R18).
// ---------------------------------------------------------------------------
__global__ __launch_bounds__(256) void attn_kernel(
    const bf16_t* __restrict__ qkv, float* __restrict__ Op,
    float* __restrict__ lp) {
  __shared__ bf16_t Ks[64 * 128];    // [key][d], chunk ^ (key&15)
  __shared__ bf16_t Vt[128 * 64];    // [d][key], chunk ^ (d&7)
  __shared__ bf16_t Ps[4 * 16 * 64]; // per-wave, chunk ^ (row&7)
  const int tid = threadIdx.x;
  const int lane = tid & 63;
  const int wave = tid >> 6;
  const int quad = lane >> 4;
  const int l15 = lane & 15;
  const int l7 = l15 & 7;
  const int j = blockIdx.x;
  const int half = j >> 9;
  const int j2 = j & 511;
  const int qb = (j2 < 256) ? (31 - (j2 >> 4)) : ((j2 - 256) >> 4);
  const int h = j2 & 15;
  const int kvh = h >> 2;
  const int nh0 = (qb + 2) >> 1;             // tiles in half 0
  const int kbS = half ? nh0 : 0;
  const int kbE = half ? (qb + 1) : nh0;
  const float scale = 0.08838834764831845f;  // 1/sqrt(128)

  // staging coordinates (iteration-invariant)
  const int rk0 = tid >> 4;        // K row within 16-row group
  const int cq = tid & 15;         // K col chunk
  const int dv2 = lane * 2;        // V d-pair base

  // Q fragments (A-operand)
  bf16x8_t qf[4];
  {
    const bf16_t* qbase =
        qkv + (size_t)(qb * 64 + wave * 16 + l15) * 3072 + h * 128 + quad * 8;
#pragma unroll
    for (int kf = 0; kf < 4; ++kf) qf[kf] = *(const bf16x8_t*)(qbase + kf * 32);
  }

  f32x4_t o[8] = {};
  float lsum[4] = {0.f, 0.f, 0.f, 0.f};

  bf16x8_t kreg[4];
  uint32_t vbuf[2][8];
  auto load_tile = [&](int kb) {
    const bf16_t* kbase = qkv + (size_t)(kb * 64) * 3072 + 2048 + kvh * 128;
    const bf16_t* vbase = qkv + (size_t)(kb * 64) * 3072 + 2560 + kvh * 128;
#pragma unroll
    for (int it = 0; it < 4; ++it)
      kreg[it] =
          *(const bf16x8_t*)(kbase + (size_t)(it * 16 + rk0) * 3072 + cq * 8);
#pragma unroll
    for (int it = 0; it < 2; ++it) {
      const int kg8 = it * 4 + wave;  // key octet 0..7
#pragma unroll
      for (int t = 0; t < 8; ++t)
        vbuf[it][t] =
            *(const uint32_t*)(vbase + (size_t)(kg8 * 8 + t) * 3072 + dv2);
    }
  };

  if (kbS < kbE) {
    load_tile(kbS);

    for (int kb = kbS; kb < kbE; ++kb) {
      __syncthreads();  // prev iteration's Ks/Vt reads complete
#pragma unroll
      for (int it = 0; it < 4; ++it)
        *(bf16x8_t*)(Ks + (it * 16 + rk0) * 128 + ((cq ^ rk0) * 8)) = kreg[it];
#pragma unroll
      for (int it = 0; it < 2; ++it) {
        const int kg8 = it * 4 + wave;
        bf16x8_t lov, hiv;
#pragma unroll
        for (int t = 0; t < 8; ++t) {
          const uint32_t u = vbuf[it][t];
          lov[t] = __builtin_bit_cast(bf16_t, (unsigned short)(u & 0xffff));
          hiv[t] = __builtin_bit_cast(bf16_t, (unsigned short)(u >> 16));
        }
        *(bf16x8_t*)(Vt + (size_t)dv2 * 64 + ((kg8 ^ (dv2 & 7)) * 8)) = lov;
        *(bf16x8_t*)(Vt + (size_t)(dv2 + 1) * 64 +
                     ((kg8 ^ ((dv2 + 1) & 7)) * 8)) = hiv;
      }
      __syncthreads();
      if (kb + 1 < kbE) load_tile(kb + 1);  // overlaps compute below

      // S = Q * K^T
      f32x4_t sc[4] = {};
      __builtin_amdgcn_s_setprio(1);
#pragma unroll
      for (int kf = 0; kf < 4; ++kf) {
#pragma unroll
        for (int ni = 0; ni < 4; ++ni) {
          bf16x8_t bfr = *(const bf16x8_t*)(Ks + (ni * 16 + l15) * 128 +
                                            (((kf * 4 + quad) ^ l15) * 8));
          sc[ni] = __builtin_amdgcn_mfma_f32_16x16x32_bf16(qf[kf], bfr, sc[ni],
                                                           0, 0, 0);
        }
      }
      __builtin_amdgcn_s_setprio(0);

      // fixed-max softmax: p = exp(s*scale - 16); causal mask -> -100 arg
      float p[4][4];
#pragma unroll
      for (int r = 0; r < 4; ++r) {
        const int sq = qb * 64 + wave * 16 + quad * 4 + r;
#pragma unroll
        for (int ni = 0; ni < 4; ++ni) {
          float arg = fmaf(sc[ni][r], scale, -16.0f);
          if (kb == qb && (kb * 64 + ni * 16 + l15) > sq) arg = -100.0f;
          const float e = __expf(arg);
          p[ni][r] = e;
          lsum[r] += e;
        }
      }

      // P: C layout -> LDS (wave-private, swizzled)
      bf16_t* pw = Ps + wave * 16 * 64;
#pragma unroll
      for (int ni = 0; ni < 4; ++ni)
#pragma unroll
        for (int r = 0; r < 4; ++r) {
          const int prow = quad * 4 + r;
          pw[prow * 64 + (((ni * 2 + (l15 >> 3)) ^ (prow & 7)) * 8) + l7] =
              (bf16_t)p[ni][r];
        }

      // O += P * V
      __builtin_amdgcn_s_setprio(1);
#pragma unroll
      for (int kf = 0; kf < 2; ++kf) {
        bf16x8_t af =
            *(const bf16x8_t*)(pw + l15 * 64 + (((kf * 4 + quad) ^ l7) * 8));
#pragma unroll
        for (int ni = 0; ni < 8; ++ni) {
          bf16x8_t bfr = *(const bf16x8_t*)(Vt + (ni * 16 + l15) * 64 +
                                            (((kf * 4 + quad) ^ l7) * 8));
          o[ni] =
              __builtin_amdgcn_mfma_f32_16x16x32_bf16(af, bfr, o[ni], 0, 0, 0);
        }
      }
      __builtin_amdgcn_s_setprio(0);
    }
  }

  // epilogue: reduce l across 16 lanes; store fp32 partials
#pragma unroll
  for (int m = 1; m <= 8; m <<= 1)
#pragma unroll
    for (int r = 0; r < 4; ++r) lsum[r] += __shfl_xor(lsum[r], m, 64);

  float* obase = Op + (size_t)half * 4194304 +
                 (size_t)(qb * 64 + wave * 16 + quad * 4) * 2048 + h * 128 + l15;
#pragma unroll
  for (int r = 0; r < 4; ++r) {
#pragma unroll
    for (int ni = 0; ni < 8; ++ni)
      obase[(size_t)r * 2048 + ni * 16] = o[ni][r];
    if (l15 == 0) {
      const int row = qb * 64 + wave * 16 + quad * 4 + r;
      lp[(half * 2048 + row) * 16 + h] = lsum[r];
    }
  }
}

// ---------------------------------------------------------------------------
// combine: out_bf16[s][col] = (O0 + O1) / (l0 + l1)  — restored (R8 numerics,
// exact 1.0f/l), widened to 8 floats/thread.
// ---------------------------------------------------------------------------
__global__ __launch_bounds__(256) void combine_kernel(
    const float* __restrict__ Op, const float* __restrict__ lp,
    bf16_t* __restrict__ out) {
  const int idx = (blockIdx.x * 256 + threadIdx.x) * 8;
  const int s = idx >> 11;
  const int col = idx & 2047;
  const int h = col >> 7;
  const float l = lp[s * 16 + h] + lp[(2048 + s) * 16 + h];
  const float inv = 1.0f / l;
  const float* pa = Op + (size_t)s * 2048 + col;
  const float* pb = pa + 4194304;
  float4 a0 = *(const float4*)(pa);
  float4 a1 = *(const float4*)(pa + 4);
  float4 b0 = *(const float4*)(pb);
  float4 b1 = *(const float4*)(pb + 4);
  bf16x8_t o = {(bf16_t)((a0.x + b0.x) * inv), (bf16_t)((a0.y + b0.y) * inv),
                (bf16_t)((a0.z + b0.z) * inv), (bf16_t)((a0.w + b0.w) * inv),
                (bf16_t)((a1.x + b1.x) * inv), (bf16_t)((a1.y + b1.y) * inv),
                (bf16_t)((a1.z + b1.z) * inv), (bf16_t)((a1.w + b1.w) * inv)};
  *(bf16x8_t*)(out + idx) = o;
}

// ---------------------------------------------------------------------------
// ws layout (~61.3 MB, liveness-reused):
//   regA  [0,    8 MB)   hs_bf16          -> combine out (attn bf16)
//   regB  [8,   20.6 MB) Wqkv_bf16        (dead after QKV gemm)
//   Opart [8,   40 MB)   fp32 O partials  (overwrites regB)
//   regC  [40,  52.6 MB) qkv bf16 (RoPE applied in GEMM epilogue)
//   regWo [53,  61 MB)   Wo_bf16
//   lpart [61,  61.25)   fp32 l partials [2][2048][16]
// ---------------------------------------------------------------------------
extern "C" void kernel_launch(void* const* d_in, const int* in_sizes, int n_in,
                              void* d_out, int out_size, void* d_ws, size_t ws_size,
                              hipStream_t stream) {
  const float* hidden = (const float*)d_in[0];
  const float* Wq = (const float*)d_in[1];
  const float* Wk = (const float*)d_in[2];
  const float* Wv = (const float*)d_in[3];
  const float* Wo = (const float*)d_in[4];

  char* ws = (char*)d_ws;
  bf16_t* regA = (bf16_t*)ws;
  bf16_t* regB = (bf16_t*)(ws + (size_t)(8u << 20));
  float* Opart = (float*)(ws + (size_t)(8u << 20));
  bf16_t* regC = (bf16_t*)(ws + (size_t)(40u << 20));
  bf16_t* regWo = (bf16_t*)(ws + (size_t)(53u << 20));
  float* lpart = (float*)(ws + (size_t)(61u << 20));

  cvt_all<<<7168, 256, 0, stream>>>(hidden, Wq, Wk, Wv, Wo, regA, regB, regWo);

  // qkv = hidden @ [Wq;Wk;Wv]^T, RoPE fused -> regC [2048,3072]
  gemm_bt64<bf16_t, true><<<dim3(32, 24), 256, 0, stream>>>(regA, regB, regC,
                                                            2048, 3072, 2048);

  attn_kernel<<<1024, 256, 0, stream>>>(regC, Opart, lpart);

  combine_kernel<<<2048, 256, 0, stream>>>(Opart, lpart, regA);

  gemm_bt64<float, false><<<dim3(32, 16), 256, 0, stream>>>(
      regA, regWo, (float*)d_out, 2048, 2048, 2048);
}

// Round 11
// 218.034 us; speedup vs baseline: 1.0125x; 1.0068x over previous
//
#include <hip/hip_runtime.h>
#include <cstdint>
#include <cstddef>

// ---------------------------------------------------------------------------
// FlashSparseAttention on MI355X (gfx950)
// Measured ladder: R8 = 211.24 us | R17 (cvt8 + fused combine + setprio)
//   = 220.76 | R18 (cvt8 + separate combine8 + setprio) = 219.52.
// R18 post-mortem: fusion revert recovered only 1.2 us -> fusion was neutral;
//   the +8 us regression lives in {cvt8, setprio, codegen noise}. absmax
//   stayed 0.015625 with exact-div combine -> numerics drift was NOT rcpf.
// R19: R18 minus attn s_setprio — single-variable A/B on the strongest
//   remaining suspect (m190 mechanism: prio-1 waves starve co-resident
//   blocks' staging on the same SIMD; this attn is 4-wave-lockstep blocks).
//   Everything else byte-identical to R18.
// ---------------------------------------------------------------------------

typedef __bf16 bf16_t;
typedef bf16_t bf16x4_t __attribute__((ext_vector_type(4)));
typedef bf16_t bf16x8_t __attribute__((ext_vector_type(8)));
typedef float f32x4_t __attribute__((ext_vector_type(4)));

__device__ __forceinline__ void async_copy16(void* lds_base, const void* gsrc) {
  auto g = reinterpret_cast<__attribute__((address_space(1))) void*>(
      reinterpret_cast<uintptr_t>(gsrc));
  auto l = reinterpret_cast<__attribute__((address_space(3))) void*>(
      static_cast<uint32_t>(reinterpret_cast<uintptr_t>(lds_base)));
  __builtin_amdgcn_global_load_lds(g, l, 16, 0, 0);
}

// ---------------------------------------------------------------------------
// fp32 -> bf16: merged conversion of hidden/Wq/Wk/Wv/Wo (one launch)
// 8 floats/thread: 2x float4 load + one 16B bf16x8 store.
// ---------------------------------------------------------------------------
__global__ __launch_bounds__(256) void cvt_all(const float* __restrict__ hs,
                                               const float* __restrict__ wq,
                                               const float* __restrict__ wk,
                                               const float* __restrict__ wv,
                                               const float* __restrict__ wo,
                                               bf16_t* __restrict__ regA,
                                               bf16_t* __restrict__ regB,
                                               bf16_t* __restrict__ regWo) {
  const int b = blockIdx.x;
  const float* src;
  bf16_t* dst;
  int rel;
  if (b < 2048) { src = hs; dst = regA; rel = b; }
  else if (b < 4096) { src = wq; dst = regB; rel = b - 2048; }
  else if (b < 4608) { src = wk; dst = regB + 4194304; rel = b - 4096; }
  else if (b < 5120) { src = wv; dst = regB + 5242880; rel = b - 4608; }
  else { src = wo; dst = regWo; rel = b - 5120; }
  const int i = (rel * 256 + threadIdx.x) * 8;
  float4 v0 = *(const float4*)(src + i);
  float4 v1 = *(const float4*)(src + i + 4);
  bf16x8_t o = {(bf16_t)v0.x, (bf16_t)v0.y, (bf16_t)v0.z, (bf16_t)v0.w,
                (bf16_t)v1.x, (bf16_t)v1.y, (bf16_t)v1.z, (bf16_t)v1.w};
  *(bf16x8_t*)(dst + i) = o;
}

// ---------------------------------------------------------------------------
// NT GEMM: C[M,N] = A[M,K] * B[N,K]^T, 64x128 tile, BK=64, 4 waves.
// LDS XOR swizzle (chunk q of row r at slot q^(r&7)); store side permutes
// the GLOBAL source address, keeping global_load_lds + coalescing.
// ROPE fused in epilogue for output cols < 2560.  (QKV projection only.)
// (byte-identical to R8 — cross-round control)
// ---------------------------------------------------------------------------
template <typename OutT, bool ROPE>
__global__ __launch_bounds__(256) void gemm_bt64(const bf16_t* __restrict__ A,
                                                 const bf16_t* __restrict__ B,
                                                 OutT* __restrict__ C,
                                                 int M, int N, int K) {
  __shared__ bf16_t As[64 * 64];
  __shared__ bf16_t Bs[128 * 64];
  const int tid = threadIdx.x;
  const int lane = tid & 63;
  const int quad = lane >> 4;
  const int l15 = lane & 15;
  const int l7 = l15 & 7;
  const int wave = tid >> 6;
  const int bm = blockIdx.x * 64;
  const int bn = blockIdx.y * 128;
  const int wm = (wave >> 1) * 32;
  const int wn32 = (wave & 1) * 32;
  const int coff[4] = {wn32, wn32 + 16, wn32 + 64, wn32 + 80};

  f32x4_t acc[2][4] = {};

  for (int k0 = 0; k0 < K; k0 += 64) {
#pragma unroll
    for (int it = 0; it < 2; ++it) {
      const int slot = it * 256 + tid;          // 16B chunk index
      const int r = slot >> 3;
      const int q = (slot & 7) ^ (r & 7);       // swizzled source chunk
      const int wbase = it * 2048 + (tid & 192) * 8;
      async_copy16(As + wbase, A + (size_t)(bm + r) * K + k0 + q * 8);
    }
#pragma unroll
    for (int it = 0; it < 4; ++it) {
      const int slot = it * 256 + tid;
      const int r = slot >> 3;
      const int q = (slot & 7) ^ (r & 7);
      const int wbase = it * 2048 + (tid & 192) * 8;
      async_copy16(Bs + wbase, B + (size_t)(bn + r) * K + k0 + q * 8);
    }
    __syncthreads();
#pragma unroll
    for (int kk = 0; kk < 64; kk += 32) {
      const int kc = kk >> 3;
      bf16x8_t af[2], bfv[4];
#pragma unroll
      for (int i = 0; i < 2; ++i)
        af[i] = *(const bf16x8_t*)(As + (wm + i * 16 + l15) * 64 +
                                   (((kc + quad) ^ l7) * 8));
#pragma unroll
      for (int i = 0; i < 4; ++i)
        bfv[i] = *(const bf16x8_t*)(Bs + (coff[i] + l15) * 64 +
                                    (((kc + quad) ^ l7) * 8));
#pragma unroll
      for (int mi = 0; mi < 2; ++mi)
#pragma unroll
        for (int ni = 0; ni < 4; ++ni)
          acc[mi][ni] = __builtin_amdgcn_mfma_f32_16x16x32_bf16(
              af[mi], bfv[ni], acc[mi][ni], 0, 0, 0);
    }
    __syncthreads();
  }

  if (ROPE && bn < 2560) {  // q/k columns; v (>=2560) skips
#pragma unroll
    for (int pair = 0; pair < 2; ++pair) {
      const int i_d = wn32 + pair * 16 + l15;  // head-relative d in [0,64)
      const float inv = exp2f(-(float)i_d * 0.20762050593045702f);
#pragma unroll
      for (int mi = 0; mi < 2; ++mi) {
#pragma unroll
        for (int r = 0; r < 4; ++r) {
          const int s_row = bm + wm + mi * 16 + quad * 4 + r;
          float sn, cs;
          sincosf((float)s_row * inv, &sn, &cs);
          const float x0 = acc[mi][pair][r];
          const float x1 = acc[mi][pair + 2][r];
          acc[mi][pair][r] = x0 * cs - x1 * sn;
          acc[mi][pair + 2][r] = x1 * cs + x0 * sn;
        }
      }
    }
  }

  // C/D layout: col = lane&15, row = quad*4 + reg
#pragma unroll
  for (int mi = 0; mi < 2; ++mi) {
#pragma unroll
    for (int r = 0; r < 4; ++r) {
      const int row = bm + wm + mi * 16 + quad * 4 + r;
#pragma unroll
      for (int ni = 0; ni < 4; ++ni)
        C[(size_t)row * N + bn + coff[ni] + l15] = (OutT)acc[mi][ni][r];
    }
  }
}

// ---------------------------------------------------------------------------
// Flash attention, causal, GQA, split-KV x2 (additive fp32 partials via
// fixed-max softmax).  1024 blocks; complementary mapping: the 4 blocks
// co-resident on a CU (j, j+256 over both halves) total exactly 33 kv-tiles.
// R6 body: register K/V prefetch during compute, 2 barriers/tile.
// XOR-swizzled LDS, no padding: exactly 40 KB.
// R19: setprio REMOVED (A/B vs R18; m190 starvation suspect).
// ---------------------------------------------------------------------------
__global__ __launch_bounds__(256) void attn_kernel(
    const bf16_t* __restrict__ qkv, float* __restrict__ Op,
    float* __restrict__ lp) {
  __shared__ bf16_t Ks[64 * 128];    // [key][d], chunk ^ (key&15)
  __shared__ bf16_t Vt[128 * 64];    // [d][key], chunk ^ (d&7)
  __shared__ bf16_t Ps[4 * 16 * 64]; // per-wave, chunk ^ (row&7)
  const int tid = threadIdx.x;
  const int lane = tid & 63;
  const int wave = tid >> 6;
  const int quad = lane >> 4;
  const int l15 = lane & 15;
  const int l7 = l15 & 7;
  const int j = blockIdx.x;
  const int half = j >> 9;
  const int j2 = j & 511;
  const int qb = (j2 < 256) ? (31 - (j2 >> 4)) : ((j2 - 256) >> 4);
  const int h = j2 & 15;
  const int kvh = h >> 2;
  const int nh0 = (qb + 2) >> 1;             // tiles in half 0
  const int kbS = half ? nh0 : 0;
  const int kbE = half ? (qb + 1) : nh0;
  const float scale = 0.08838834764831845f;  // 1/sqrt(128)

  // staging coordinates (iteration-invariant)
  const int rk0 = tid >> 4;        // K row within 16-row group
  const int cq = tid & 15;         // K col chunk
  const int dv2 = lane * 2;        // V d-pair base

  // Q fragments (A-operand)
  bf16x8_t qf[4];
  {
    const bf16_t* qbase =
        qkv + (size_t)(qb * 64 + wave * 16 + l15) * 3072 + h * 128 + quad * 8;
#pragma unroll
    for (int kf = 0; kf < 4; ++kf) qf[kf] = *(const bf16x8_t*)(qbase + kf * 32);
  }

  f32x4_t o[8] = {};
  float lsum[4] = {0.f, 0.f, 0.f, 0.f};

  bf16x8_t kreg[4];
  uint32_t vbuf[2][8];
  auto load_tile = [&](int kb) {
    const bf16_t* kbase = qkv + (size_t)(kb * 64) * 3072 + 2048 + kvh * 128;
    const bf16_t* vbase = qkv + (size_t)(kb * 64) * 3072 + 2560 + kvh * 128;
#pragma unroll
    for (int it = 0; it < 4; ++it)
      kreg[it] =
          *(const bf16x8_t*)(kbase + (size_t)(it * 16 + rk0) * 3072 + cq * 8);
#pragma unroll
    for (int it = 0; it < 2; ++it) {
      const int kg8 = it * 4 + wave;  // key octet 0..7
#pragma unroll
      for (int t = 0; t < 8; ++t)
        vbuf[it][t] =
            *(const uint32_t*)(vbase + (size_t)(kg8 * 8 + t) * 3072 + dv2);
    }
  };

  if (kbS < kbE) {
    load_tile(kbS);

    for (int kb = kbS; kb < kbE; ++kb) {
      __syncthreads();  // prev iteration's Ks/Vt reads complete
#pragma unroll
      for (int it = 0; it < 4; ++it)
        *(bf16x8_t*)(Ks + (it * 16 + rk0) * 128 + ((cq ^ rk0) * 8)) = kreg[it];
#pragma unroll
      for (int it = 0; it < 2; ++it) {
        const int kg8 = it * 4 + wave;
        bf16x8_t lov, hiv;
#pragma unroll
        for (int t = 0; t < 8; ++t) {
          const uint32_t u = vbuf[it][t];
          lov[t] = __builtin_bit_cast(bf16_t, (unsigned short)(u & 0xffff));
          hiv[t] = __builtin_bit_cast(bf16_t, (unsigned short)(u >> 16));
        }
        *(bf16x8_t*)(Vt + (size_t)dv2 * 64 + ((kg8 ^ (dv2 & 7)) * 8)) = lov;
        *(bf16x8_t*)(Vt + (size_t)(dv2 + 1) * 64 +
                     ((kg8 ^ ((dv2 + 1) & 7)) * 8)) = hiv;
      }
      __syncthreads();
      if (kb + 1 < kbE) load_tile(kb + 1);  // overlaps compute below

      // S = Q * K^T
      f32x4_t sc[4] = {};
#pragma unroll
      for (int kf = 0; kf < 4; ++kf) {
#pragma unroll
        for (int ni = 0; ni < 4; ++ni) {
          bf16x8_t bfr = *(const bf16x8_t*)(Ks + (ni * 16 + l15) * 128 +
                                            (((kf * 4 + quad) ^ l15) * 8));
          sc[ni] = __builtin_amdgcn_mfma_f32_16x16x32_bf16(qf[kf], bfr, sc[ni],
                                                           0, 0, 0);
        }
      }

      // fixed-max softmax: p = exp(s*scale - 16); causal mask -> -100 arg
      float p[4][4];
#pragma unroll
      for (int r = 0; r < 4; ++r) {
        const int sq = qb * 64 + wave * 16 + quad * 4 + r;
#pragma unroll
        for (int ni = 0; ni < 4; ++ni) {
          float arg = fmaf(sc[ni][r], scale, -16.0f);
          if (kb == qb && (kb * 64 + ni * 16 + l15) > sq) arg = -100.0f;
          const float e = __expf(arg);
          p[ni][r] = e;
          lsum[r] += e;
        }
      }

      // P: C layout -> LDS (wave-private, swizzled)
      bf16_t* pw = Ps + wave * 16 * 64;
#pragma unroll
      for (int ni = 0; ni < 4; ++ni)
#pragma unroll
        for (int r = 0; r < 4; ++r) {
          const int prow = quad * 4 + r;
          pw[prow * 64 + (((ni * 2 + (l15 >> 3)) ^ (prow & 7)) * 8) + l7] =
              (bf16_t)p[ni][r];
        }

      // O += P * V
#pragma unroll
      for (int kf = 0; kf < 2; ++kf) {
        bf16x8_t af =
            *(const bf16x8_t*)(pw + l15 * 64 + (((kf * 4 + quad) ^ l7) * 8));
#pragma unroll
        for (int ni = 0; ni < 8; ++ni) {
          bf16x8_t bfr = *(const bf16x8_t*)(Vt + (ni * 16 + l15) * 64 +
                                            (((kf * 4 + quad) ^ l7) * 8));
          o[ni] =
              __builtin_amdgcn_mfma_f32_16x16x32_bf16(af, bfr, o[ni], 0, 0, 0);
        }
      }
    }
  }

  // epilogue: reduce l across 16 lanes; store fp32 partials
#pragma unroll
  for (int m = 1; m <= 8; m <<= 1)
#pragma unroll
    for (int r = 0; r < 4; ++r) lsum[r] += __shfl_xor(lsum[r], m, 64);

  float* obase = Op + (size_t)half * 4194304 +
                 (size_t)(qb * 64 + wave * 16 + quad * 4) * 2048 + h * 128 + l15;
#pragma unroll
  for (int r = 0; r < 4; ++r) {
#pragma unroll
    for (int ni = 0; ni < 8; ++ni)
      obase[(size_t)r * 2048 + ni * 16] = o[ni][r];
    if (l15 == 0) {
      const int row = qb * 64 + wave * 16 + quad * 4 + r;
      lp[(half * 2048 + row) * 16 + h] = lsum[r];
    }
  }
}

// ---------------------------------------------------------------------------
// combine: out_bf16[s][col] = (O0 + O1) / (l0 + l1)  — R8 numerics (1.0f/l),
// 8 floats/thread.
// ---------------------------------------------------------------------------
__global__ __launch_bounds__(256) void combine_kernel(
    const float* __restrict__ Op, const float* __restrict__ lp,
    bf16_t* __restrict__ out) {
  const int idx = (blockIdx.x * 256 + threadIdx.x) * 8;
  const int s = idx >> 11;
  const int col = idx & 2047;
  const int h = col >> 7;
  const float l = lp[s * 16 + h] + lp[(2048 + s) * 16 + h];
  const float inv = 1.0f / l;
  const float* pa = Op + (size_t)s * 2048 + col;
  const float* pb = pa + 4194304;
  float4 a0 = *(const float4*)(pa);
  float4 a1 = *(const float4*)(pa + 4);
  float4 b0 = *(const float4*)(pb);
  float4 b1 = *(const float4*)(pb + 4);
  bf16x8_t o = {(bf16_t)((a0.x + b0.x) * inv), (bf16_t)((a0.y + b0.y) * inv),
                (bf16_t)((a0.z + b0.z) * inv), (bf16_t)((a0.w + b0.w) * inv),
                (bf16_t)((a1.x + b1.x) * inv), (bf16_t)((a1.y + b1.y) * inv),
                (bf16_t)((a1.z + b1.z) * inv), (bf16_t)((a1.w + b1.w) * inv)};
  *(bf16x8_t*)(out + idx) = o;
}

// ---------------------------------------------------------------------------
// ws layout (~61.3 MB, liveness-reused):
//   regA  [0,    8 MB)   hs_bf16          -> combine out (attn bf16)
//   regB  [8,   20.6 MB) Wqkv_bf16        (dead after QKV gemm)
//   Opart [8,   40 MB)   fp32 O partials  (overwrites regB)
//   regC  [40,  52.6 MB) qkv bf16 (RoPE applied in GEMM epilogue)
//   regWo [53,  61 MB)   Wo_bf16
//   lpart [61,  61.25)   fp32 l partials [2][2048][16]
// ---------------------------------------------------------------------------
extern "C" void kernel_launch(void* const* d_in, const int* in_sizes, int n_in,
                              void* d_out, int out_size, void* d_ws, size_t ws_size,
                              hipStream_t stream) {
  const float* hidden = (const float*)d_in[0];
  const float* Wq = (const float*)d_in[1];
  const float* Wk = (const float*)d_in[2];
  const float* Wv = (const float*)d_in[3];
  const float* Wo = (const float*)d_in[4];

  char* ws = (char*)d_ws;
  bf16_t* regA = (bf16_t*)ws;
  bf16_t* regB = (bf16_t*)(ws + (size_t)(8u << 20));
  float* Opart = (float*)(ws + (size_t)(8u << 20));
  bf16_t* regC = (bf16_t*)(ws + (size_t)(40u << 20));
  bf16_t* regWo = (bf16_t*)(ws + (size_t)(53u << 20));
  float* lpart = (float*)(ws + (size_t)(61u << 20));

  cvt_all<<<7168, 256, 0, stream>>>(hidden, Wq, Wk, Wv, Wo, regA, regB, regWo);

  // qkv = hidden @ [Wq;Wk;Wv]^T, RoPE fused -> regC [2048,3072]
  gemm_bt64<bf16_t, true><<<dim3(32, 24), 256, 0, stream>>>(regA, regB, regC,
                                                            2048, 3072, 2048);

  attn_kernel<<<1024, 256, 0, stream>>>(regC, Opart, lpart);

  combine_kernel<<<2048, 256, 0, stream>>>(Opart, lpart, regA);

  gemm_bt64<float, false><<<dim3(32, 16), 256, 0, stream>>>(
      regA, regWo, (float*)d_out, 2048, 2048, 2048);
}